// Round 1
// 534.294 us; speedup vs baseline: 1.0328x; 1.0328x over previous
//
#include <hip/hip_runtime.h>

// AdaPool2D: 2x2 stride-2 window, blend of exp-softmax pooling and
// Dice-Sorensen-softmax pooling.
//   inputs: [B=32, W=224, H=224, C=64] fp32 (C contiguous innermost)
//   mask:   [1] fp32 blend scalar
//   out:    [B, 112, 112, 64] fp32
//
// Streaming op: 411 MB in + 103 MB out, every input element read exactly once.
// One thread = one (b, wo, ho..ho+1) pair of spatial outputs x 4 channels:
//   - 8 float4 nontemporal loads in flight (2x the MLP of the previous version)
//   - 2 float4 nontemporal stores
//   - halves thread count; index math + mask load amortized over 2 outputs.

constexpr int Bn = 32;
constexpr int Wd = 224;
constexpr int Hd = 224;
constexpr int Cd = 64;
constexpr int Wo = 112;
constexpr int Ho = 112;
constexpr int Ho2 = Ho / 2;                        // 56 output-pairs along ho
constexpr int HC = Hd * Cd;                        // 14336: W-row stride in floats
constexpr int TOTAL = Bn * Wo * Ho2 * (Cd / 4);    // 3,211,264 work items

using f32x4 = __attribute__((ext_vector_type(4))) float;

__device__ __forceinline__ f32x4 pool_win(f32x4 a4, f32x4 b4, f32x4 c4v, f32x4 d4,
                                          float m, float m1) {
    f32x4 r;
#pragma unroll
    for (int k = 0; k < 4; ++k) {
        float a = a4[k], bb = b4[k], cc = c4v[k], dd = d4[k];

        // exponential-maximum pooling: sum(p * softmax(p))
        float ea = __expf(a), eb = __expf(bb), ec = __expf(cc), ed = __expf(dd);
        float inv_se = __builtin_amdgcn_rcpf(ea + eb + ec + ed);
        float em = (a * ea + bb * eb + cc * ec + dd * ed) * inv_se;

        // eDSCW pooling: dsc = 2*avg*p / (avg^2 + p^2), softmax over window
        float avg  = 0.25f * (a + bb + cc + dd);
        float avg2 = avg * avg;
        float ta   = 2.0f * avg;
        float da = ta * a  * __builtin_amdgcn_rcpf(avg2 + a  * a);
        float db = ta * bb * __builtin_amdgcn_rcpf(avg2 + bb * bb);
        float dc = ta * cc * __builtin_amdgcn_rcpf(avg2 + cc * cc);
        float de = ta * dd * __builtin_amdgcn_rcpf(avg2 + dd * dd);
        float fa = __expf(da), fb = __expf(db), fc = __expf(dc), fd = __expf(de);
        float inv_sd = __builtin_amdgcn_rcpf(fa + fb + fc + fd);
        float dp = (a * fa + bb * fb + cc * fc + dd * fd) * inv_sd;

        r[k] = em * m + dp * m1;
    }
    return r;
}

__global__ __launch_bounds__(256)
void adapool2d_kernel(const float* __restrict__ in,
                      const float* __restrict__ mask,
                      float* __restrict__ out) {
    int i = blockIdx.x * 256 + threadIdx.x;
    if (i >= TOTAL) return;

    const float m  = mask[0];          // uniform -> scalar load
    const float m1 = 1.0f - m;

    // i = ((b*Wo + wo)*Ho2 + h2)*16 + c4/4
    int c4 = (i & 15) * 4;
    int t  = i >> 4;
    int h2 = t % Ho2;
    t      = t / Ho2;
    int wo = t % Wo;
    int b  = t / Wo;
    int ho = h2 * 2;                   // first of the two output columns

    // Input base: row 2*wo, col 2*ho. This thread consumes input cols
    // 2ho..2ho+3 on rows 2wo and 2wo+1 (no overlap with neighbor threads).
    const float* p = in + (size_t)(b * Wd + 2 * wo) * HC + (2 * ho) * Cd + c4;
    const f32x4* q0 = reinterpret_cast<const f32x4*>(p);        // row 2wo
    const f32x4* q1 = reinterpret_cast<const f32x4*>(p + HC);   // row 2wo+1

    // f32x4 pointer stride of 16 == Cd floats == one input column.
    f32x4 v00 = __builtin_nontemporal_load(q0);        // (2wo  , 2ho  )
    f32x4 v01 = __builtin_nontemporal_load(q0 + 16);   // (2wo  , 2ho+1)
    f32x4 v02 = __builtin_nontemporal_load(q0 + 32);   // (2wo  , 2ho+2)
    f32x4 v03 = __builtin_nontemporal_load(q0 + 48);   // (2wo  , 2ho+3)
    f32x4 v10 = __builtin_nontemporal_load(q1);        // (2wo+1, 2ho  )
    f32x4 v11 = __builtin_nontemporal_load(q1 + 16);   // (2wo+1, 2ho+1)
    f32x4 v12 = __builtin_nontemporal_load(q1 + 32);   // (2wo+1, 2ho+2)
    f32x4 v13 = __builtin_nontemporal_load(q1 + 48);   // (2wo+1, 2ho+3)

    f32x4 r0 = pool_win(v00, v01, v10, v11, m, m1);    // output (wo, ho)
    f32x4 r1 = pool_win(v02, v03, v12, v13, m, m1);    // output (wo, ho+1)

    // Output float4 index: ((b*Wo + wo)*Ho + ho)*16 + c4/4 ; second output +16.
    size_t o = ((size_t)(b * Wo + wo) * Ho + ho) * 16 + (c4 >> 2);
    f32x4* op = reinterpret_cast<f32x4*>(out);
    __builtin_nontemporal_store(r0, op + o);
    __builtin_nontemporal_store(r1, op + o + 16);
}

extern "C" void kernel_launch(void* const* d_in, const int* in_sizes, int n_in,
                              void* d_out, int out_size, void* d_ws, size_t ws_size,
                              hipStream_t stream) {
    const float* in   = (const float*)d_in[0];
    const float* mask = (const float*)d_in[1];
    float* out        = (float*)d_out;

    constexpr int threads = 256;
    constexpr int blocks  = (TOTAL + threads - 1) / threads;  // 12544
    adapool2d_kernel<<<blocks, threads, 0, stream>>>(in, mask, out);
}